// Round 3
// baseline (1673.464 us; speedup 1.0000x reference)
//
#include <hip/hip_runtime.h>
#include <math.h>

#define L_  1024
#define S_  2048
#define NB  4
#define E_  512
#define H_  8
#define HD_ 64

constexpr float SCALING = 0.125f;   // (E/H)^-0.5 = 1/8
constexpr float LNEPS   = 1e-5f;

// ---------------------------------------------------------------------------
// GEMM tile core: 64x64 C-tile, BK=16, 256 threads, 4x4 acc per thread.
// C[m][c] = sum_k A[m][k] * W[c][k]   (B^T layout: W rows are output cols)
// ---------------------------------------------------------------------------

// Kernel 1: q = (query @ Wq^T + bq) * scaling, then rotary, scatter to [N][H][L][64]
__global__ __launch_bounds__(256)
void qproj_rotary_kernel(const float* __restrict__ A,      // (L*NB, E)
                         const float* __restrict__ W,      // (E, E) rows 0..E-1
                         const float* __restrict__ bias,   // (E)
                         const float* __restrict__ qpos,   // (NB, L, E, 2)
                         float* __restrict__ qrot)         // (NB, H, L, 64)
{
    __shared__ float As[64][17];
    __shared__ float Bs[64][17];
    const int t  = threadIdx.x;
    const int m0 = blockIdx.y * 64;
    const int c0 = blockIdx.x * 64;
    const int tx = t & 15, ty = t >> 4;
    const int lr = t >> 2, lc = (t & 3) * 4;
    float acc[4][4] = {};

    for (int k0 = 0; k0 < E_; k0 += 16) {
        float4 av = *reinterpret_cast<const float4*>(&A[(m0 + lr) * E_ + k0 + lc]);
        float4 bv = *reinterpret_cast<const float4*>(&W[(c0 + lr) * E_ + k0 + lc]);
        As[lr][lc + 0] = av.x; As[lr][lc + 1] = av.y; As[lr][lc + 2] = av.z; As[lr][lc + 3] = av.w;
        Bs[lr][lc + 0] = bv.x; Bs[lr][lc + 1] = bv.y; Bs[lr][lc + 2] = bv.z; Bs[lr][lc + 3] = bv.w;
        __syncthreads();
        #pragma unroll
        for (int kk = 0; kk < 16; ++kk) {
            float a[4], b[4];
            #pragma unroll
            for (int i = 0; i < 4; ++i) a[i] = As[ty * 4 + i][kk];
            #pragma unroll
            for (int j = 0; j < 4; ++j) b[j] = Bs[tx * 4 + j][kk];
            #pragma unroll
            for (int i = 0; i < 4; ++i)
                #pragma unroll
                for (int j = 0; j < 4; ++j) acc[i][j] += a[i] * b[j];
        }
        __syncthreads();
    }

    #pragma unroll
    for (int i = 0; i < 4; ++i) {
        const int m = m0 + ty * 4 + i;
        const int l = m >> 2;          // m / NB
        const int n = m & 3;           // m % NB
        #pragma unroll
        for (int jp = 0; jp < 2; ++jp) {
            const int e0 = c0 + tx * 4 + jp * 2;
            float v0 = (acc[i][jp * 2 + 0] + bias[e0 + 0]) * SCALING;
            float v1 = (acc[i][jp * 2 + 1] + bias[e0 + 1]) * SCALING;
            const int pb = ((n * L_ + l) * E_ + e0) * 2;
            float c0v = qpos[pb + 0], s0v = qpos[pb + 1];
            float c1v = qpos[pb + 2], s1v = qpos[pb + 3];
            float o0 = v0 * c0v - v1 * s0v;
            float o1 = v1 * c1v + v0 * s1v;
            const int h = e0 >> 6, hd = e0 & 63;
            const int ob = ((n * H_ + h) * L_ + l) * HD_ + hd;
            qrot[ob]     = o0;
            qrot[ob + 1] = o1;
        }
    }
}

// Kernel 2: kv = value @ Wkv^T + bkv; cols<E -> K (+rotary), cols>=E -> V
__global__ __launch_bounds__(256)
void kvproj_rotary_kernel(const float* __restrict__ A,      // (S*NB, E)
                          const float* __restrict__ W,      // (2E, E)  (ipw + E*E)
                          const float* __restrict__ bias,   // (2E)     (ipb + E)
                          const float* __restrict__ vpos,   // (NB, S, E, 2)
                          float* __restrict__ krot,         // (NB, H, S, 64)
                          float* __restrict__ vperm)        // (NB, H, S, 64)
{
    __shared__ float As[64][17];
    __shared__ float Bs[64][17];
    const int t  = threadIdx.x;
    const int m0 = blockIdx.y * 64;
    const int c0 = blockIdx.x * 64;
    const int tx = t & 15, ty = t >> 4;
    const int lr = t >> 2, lc = (t & 3) * 4;
    float acc[4][4] = {};

    for (int k0 = 0; k0 < E_; k0 += 16) {
        float4 av = *reinterpret_cast<const float4*>(&A[(m0 + lr) * E_ + k0 + lc]);
        float4 bv = *reinterpret_cast<const float4*>(&W[(c0 + lr) * E_ + k0 + lc]);
        As[lr][lc + 0] = av.x; As[lr][lc + 1] = av.y; As[lr][lc + 2] = av.z; As[lr][lc + 3] = av.w;
        Bs[lr][lc + 0] = bv.x; Bs[lr][lc + 1] = bv.y; Bs[lr][lc + 2] = bv.z; Bs[lr][lc + 3] = bv.w;
        __syncthreads();
        #pragma unroll
        for (int kk = 0; kk < 16; ++kk) {
            float a[4], b[4];
            #pragma unroll
            for (int i = 0; i < 4; ++i) a[i] = As[ty * 4 + i][kk];
            #pragma unroll
            for (int j = 0; j < 4; ++j) b[j] = Bs[tx * 4 + j][kk];
            #pragma unroll
            for (int i = 0; i < 4; ++i)
                #pragma unroll
                for (int j = 0; j < 4; ++j) acc[i][j] += a[i] * b[j];
        }
        __syncthreads();
    }

    #pragma unroll
    for (int i = 0; i < 4; ++i) {
        const int m = m0 + ty * 4 + i;
        const int s = m >> 2;
        const int n = m & 3;
        const int col0 = c0 + tx * 4;
        if (col0 < E_) {  // K half: bias + rotary
            #pragma unroll
            for (int jp = 0; jp < 2; ++jp) {
                const int e0 = col0 + jp * 2;
                float v0 = acc[i][jp * 2 + 0] + bias[e0 + 0];
                float v1 = acc[i][jp * 2 + 1] + bias[e0 + 1];
                const int pb = ((n * S_ + s) * E_ + e0) * 2;
                float c0v = vpos[pb + 0], s0v = vpos[pb + 1];
                float c1v = vpos[pb + 2], s1v = vpos[pb + 3];
                float o0 = v0 * c0v - v1 * s0v;
                float o1 = v1 * c1v + v0 * s1v;
                const int h = e0 >> 6, hd = e0 & 63;
                const int ob = ((n * H_ + h) * S_ + s) * HD_ + hd;
                krot[ob]     = o0;
                krot[ob + 1] = o1;
            }
        } else {          // V half: bias only
            #pragma unroll
            for (int j = 0; j < 4; ++j) {
                const int e = col0 - E_ + j;
                float v = acc[i][j] + bias[col0 + j];
                const int h = e >> 6, hd = e & 63;
                vperm[((n * H_ + h) * S_ + s) * HD_ + hd] = v;
            }
        }
    }
}

// Kernel 3: flash attention. block = (n, h, 32 q rows). 256 threads.
__global__ __launch_bounds__(256)
void attn_kernel(const float* __restrict__ qr,   // (NB,H,L,64)
                 const float* __restrict__ kr,   // (NB,H,S,64)
                 const float* __restrict__ vp,   // (NB,H,S,64)
                 float* __restrict__ ctx)        // (L, NB, E)
{
    __shared__ float Qs[32][65];
    __shared__ float Ks[32][65];
    __shared__ float Vs[32][65];
    __shared__ float Ps[32][33];
    __shared__ float mrun[32], lrun[32], scl[32];

    const int t  = threadIdx.x;
    const int l0 = blockIdx.x * 32;
    const int h  = blockIdx.y;
    const int n  = blockIdx.z;

    const int qb = ((n * H_ + h) * L_ + l0) * HD_;
    const int kb = ((n * H_ + h) * S_) * HD_;
    const int vb = kb;

    for (int idx = t; idx < 32 * 64; idx += 256) {
        Qs[idx >> 6][idx & 63] = qr[qb + idx];
    }
    if (t < 32) { mrun[t] = -1e30f; lrun[t] = 0.0f; }

    const int r_o = t >> 3;          // 0..31 output row
    const int c_o = (t & 7) * 8;     // 0..56 output col base
    float acc[8] = {};
    __syncthreads();

    for (int st = 0; st < S_ / 32; ++st) {
        const int s0 = st * 32;
        for (int idx = t; idx < 32 * 64; idx += 256) {
            const int r = idx >> 6, c = idx & 63;
            Ks[r][c] = kr[kb + s0 * HD_ + idx];
            Vs[r][c] = vp[vb + s0 * HD_ + idx];
        }
        __syncthreads();
        // scores: 32x32 dots of length 64
        for (int idx = t; idx < 32 * 32; idx += 256) {
            const int qi = idx >> 5, sj = idx & 31;
            float s = 0.0f;
            #pragma unroll 4
            for (int d = 0; d < 64; ++d) s += Qs[qi][d] * Ks[sj][d];
            Ps[qi][sj] = s;
        }
        __syncthreads();
        // online softmax row update (serial per row, t<32)
        if (t < 32) {
            float mx = mrun[t];
            #pragma unroll 4
            for (int j = 0; j < 32; ++j) mx = fmaxf(mx, Ps[t][j]);
            float sc = __expf(mrun[t] - mx);
            float ssum = 0.0f;
            #pragma unroll 4
            for (int j = 0; j < 32; ++j) {
                float p = __expf(Ps[t][j] - mx);
                Ps[t][j] = p;
                ssum += p;
            }
            lrun[t] = lrun[t] * sc + ssum;
            mrun[t] = mx;
            scl[t]  = sc;
        }
        __syncthreads();
        // rescale + P*V
        const float sc = scl[r_o];
        #pragma unroll
        for (int j = 0; j < 8; ++j) acc[j] *= sc;
        for (int sj = 0; sj < 32; ++sj) {
            const float p = Ps[r_o][sj];
            #pragma unroll
            for (int j = 0; j < 8; ++j) acc[j] += p * Vs[sj][c_o + j];
        }
        __syncthreads();
    }

    const float inv = 1.0f / lrun[r_o];
    #pragma unroll
    for (int j = 0; j < 8; ++j) {
        ctx[((l0 + r_o) * NB + n) * E_ + h * HD_ + c_o + j] = acc[j] * inv;
    }
}

// Kernel 4: out = ctx @ Wout^T + bout + query  -> d_out (pre-LN)
__global__ __launch_bounds__(256)
void outproj_kernel(const float* __restrict__ A,      // (L*NB, E) ctx
                    const float* __restrict__ W,      // (E, E)
                    const float* __restrict__ bias,   // (E)
                    const float* __restrict__ resid,  // (L*NB, E) query
                    float* __restrict__ Y)            // (L*NB, E)
{
    __shared__ float As[64][17];
    __shared__ float Bs[64][17];
    const int t  = threadIdx.x;
    const int m0 = blockIdx.y * 64;
    const int c0 = blockIdx.x * 64;
    const int tx = t & 15, ty = t >> 4;
    const int lr = t >> 2, lc = (t & 3) * 4;
    float acc[4][4] = {};

    for (int k0 = 0; k0 < E_; k0 += 16) {
        float4 av = *reinterpret_cast<const float4*>(&A[(m0 + lr) * E_ + k0 + lc]);
        float4 bv = *reinterpret_cast<const float4*>(&W[(c0 + lr) * E_ + k0 + lc]);
        As[lr][lc + 0] = av.x; As[lr][lc + 1] = av.y; As[lr][lc + 2] = av.z; As[lr][lc + 3] = av.w;
        Bs[lr][lc + 0] = bv.x; Bs[lr][lc + 1] = bv.y; Bs[lr][lc + 2] = bv.z; Bs[lr][lc + 3] = bv.w;
        __syncthreads();
        #pragma unroll
        for (int kk = 0; kk < 16; ++kk) {
            float a[4], b[4];
            #pragma unroll
            for (int i = 0; i < 4; ++i) a[i] = As[ty * 4 + i][kk];
            #pragma unroll
            for (int j = 0; j < 4; ++j) b[j] = Bs[tx * 4 + j][kk];
            #pragma unroll
            for (int i = 0; i < 4; ++i)
                #pragma unroll
                for (int j = 0; j < 4; ++j) acc[i][j] += a[i] * b[j];
        }
        __syncthreads();
    }

    #pragma unroll
    for (int i = 0; i < 4; ++i) {
        const int m = m0 + ty * 4 + i;
        #pragma unroll
        for (int j = 0; j < 4; ++j) {
            const int e = c0 + tx * 4 + j;
            Y[m * E_ + e] = acc[i][j] + bias[e] + resid[m * E_ + e];
        }
    }
}

// Kernel 5: in-place LayerNorm over last dim (E=512), one block per row.
__global__ __launch_bounds__(256)
void ln_kernel(float* __restrict__ y, const float* __restrict__ gamma,
               const float* __restrict__ beta)
{
    __shared__ float red1[4], red2[4];
    const int row = blockIdx.x;
    const int t   = threadIdx.x;
    float* p = y + (size_t)row * E_;
    float x0 = p[t], x1 = p[t + 256];

    float s = x0 + x1;
    #pragma unroll
    for (int o = 32; o >= 1; o >>= 1) s += __shfl_down(s, o, 64);
    if ((t & 63) == 0) red1[t >> 6] = s;
    __syncthreads();
    const float mu = (red1[0] + red1[1] + red1[2] + red1[3]) * (1.0f / E_);

    const float d0 = x0 - mu, d1 = x1 - mu;
    float vs = d0 * d0 + d1 * d1;
    #pragma unroll
    for (int o = 32; o >= 1; o >>= 1) vs += __shfl_down(vs, o, 64);
    if ((t & 63) == 0) red2[t >> 6] = vs;
    __syncthreads();
    const float var  = (red2[0] + red2[1] + red2[2] + red2[3]) * (1.0f / E_);
    const float rstd = rsqrtf(var + LNEPS);

    p[t]       = d0 * rstd * gamma[t]       + beta[t];
    p[t + 256] = d1 * rstd * gamma[t + 256] + beta[t + 256];
}

extern "C" void kernel_launch(void* const* d_in, const int* in_sizes, int n_in,
                              void* d_out, int out_size, void* d_ws, size_t ws_size,
                              hipStream_t stream) {
    const float* query = (const float*)d_in[0];
    const float* value = (const float*)d_in[1];
    const float* qpos  = (const float*)d_in[2];
    const float* vpos  = (const float*)d_in[3];
    const float* ipw   = (const float*)d_in[4];
    const float* ipb   = (const float*)d_in[5];
    const float* opw   = (const float*)d_in[6];
    const float* opb   = (const float*)d_in[7];
    const float* gamma = (const float*)d_in[8];
    const float* beta  = (const float*)d_in[9];
    float* out = (float*)d_out;

    float* qrot  = (float*)d_ws;                               // NB*H*L*64  = 2M floats
    float* krot  = qrot  + (size_t)NB * H_ * L_ * HD_;         // NB*H*S*64  = 4M floats
    float* vperm = krot  + (size_t)NB * H_ * S_ * HD_;         // NB*H*S*64  = 4M floats
    float* ctx   = vperm + (size_t)NB * H_ * S_ * HD_;         // L*NB*E     = 2M floats

    qproj_rotary_kernel<<<dim3(E_ / 64, (L_ * NB) / 64), 256, 0, stream>>>(
        query, ipw, ipb, qpos, qrot);
    kvproj_rotary_kernel<<<dim3((2 * E_) / 64, (S_ * NB) / 64), 256, 0, stream>>>(
        value, ipw + E_ * E_, ipb + E_, vpos, krot, vperm);
    attn_kernel<<<dim3(L_ / 32, H_, NB), 256, 0, stream>>>(qrot, krot, vperm, ctx);
    outproj_kernel<<<dim3(E_ / 64, (L_ * NB) / 64), 256, 0, stream>>>(
        ctx, opw, opb, query, out);
    ln_kernel<<<L_ * NB, 256, 0, stream>>>(out, gamma, beta);
}

// Round 4
// 494.967 us; speedup vs baseline: 3.3810x; 3.3810x over previous
//
#include <hip/hip_runtime.h>
#include <math.h>

#define L_  1024
#define S_  2048
#define NB  4
#define E_  512
#define H_  8
#define HD_ 64

constexpr float SCALING = 0.125f;   // (E/H)^-0.5 = 1/8
constexpr float LNEPS   = 1e-5f;

typedef __attribute__((ext_vector_type(8))) short s16x8;  // 8 bf16 (4 VGPRs) MFMA frag
typedef __attribute__((ext_vector_type(4))) float f32x4;  // MFMA accumulator
typedef unsigned short ushort_t;

__device__ __forceinline__ unsigned short f2bf(float f) {
    unsigned u = __builtin_bit_cast(unsigned, f);
    u += 0x7fffu + ((u >> 16) & 1u);   // RNE
    return (unsigned short)(u >> 16);
}

// ---------------------------------------------------------------------------
// Kernel 1: q = (query @ Wq^T + bq) * scaling, rotary, -> bf16 [N][H][L][64]
// ---------------------------------------------------------------------------
__global__ __launch_bounds__(256)
void qproj_rotary_kernel(const float* __restrict__ A,      // (L*NB, E)
                         const float* __restrict__ W,      // (E, E)
                         const float* __restrict__ bias,   // (E)
                         const float* __restrict__ qpos,   // (NB, L, E, 2)
                         ushort_t* __restrict__ qrot)      // (NB, H, L, 64) bf16
{
    __shared__ float As[64][17];
    __shared__ float Bs[64][17];
    const int t  = threadIdx.x;
    const int m0 = blockIdx.y * 64;
    const int c0 = blockIdx.x * 64;
    const int tx = t & 15, ty = t >> 4;
    const int lr = t >> 2, lc = (t & 3) * 4;
    float acc[4][4] = {};

    for (int k0 = 0; k0 < E_; k0 += 16) {
        float4 av = *reinterpret_cast<const float4*>(&A[(m0 + lr) * E_ + k0 + lc]);
        float4 bv = *reinterpret_cast<const float4*>(&W[(c0 + lr) * E_ + k0 + lc]);
        As[lr][lc + 0] = av.x; As[lr][lc + 1] = av.y; As[lr][lc + 2] = av.z; As[lr][lc + 3] = av.w;
        Bs[lr][lc + 0] = bv.x; Bs[lr][lc + 1] = bv.y; Bs[lr][lc + 2] = bv.z; Bs[lr][lc + 3] = bv.w;
        __syncthreads();
        #pragma unroll
        for (int kk = 0; kk < 16; ++kk) {
            float a[4], b[4];
            #pragma unroll
            for (int i = 0; i < 4; ++i) a[i] = As[ty * 4 + i][kk];
            #pragma unroll
            for (int j = 0; j < 4; ++j) b[j] = Bs[tx * 4 + j][kk];
            #pragma unroll
            for (int i = 0; i < 4; ++i)
                #pragma unroll
                for (int j = 0; j < 4; ++j) acc[i][j] += a[i] * b[j];
        }
        __syncthreads();
    }

    #pragma unroll
    for (int i = 0; i < 4; ++i) {
        const int m = m0 + ty * 4 + i;
        const int l = m >> 2;
        const int n = m & 3;
        #pragma unroll
        for (int jp = 0; jp < 2; ++jp) {
            const int e0 = c0 + tx * 4 + jp * 2;
            float v0 = (acc[i][jp * 2 + 0] + bias[e0 + 0]) * SCALING;
            float v1 = (acc[i][jp * 2 + 1] + bias[e0 + 1]) * SCALING;
            const int pb = ((n * L_ + l) * E_ + e0) * 2;
            float c0v = qpos[pb + 0], s0v = qpos[pb + 1];
            float c1v = qpos[pb + 2], s1v = qpos[pb + 3];
            float o0 = v0 * c0v - v1 * s0v;
            float o1 = v1 * c1v + v0 * s1v;
            const int hq = e0 >> 6, hd = e0 & 63;
            ushort2 ov; ov.x = f2bf(o0); ov.y = f2bf(o1);
            *(ushort2*)&qrot[((n * H_ + hq) * L_ + l) * HD_ + hd] = ov;
        }
    }
}

// ---------------------------------------------------------------------------
// Kernel 2: kv = value @ Wkv^T + bkv; K half rotary -> bf16; V half -> bf16
// ---------------------------------------------------------------------------
__global__ __launch_bounds__(256)
void kvproj_rotary_kernel(const float* __restrict__ A,      // (S*NB, E)
                          const float* __restrict__ W,      // (2E, E)
                          const float* __restrict__ bias,   // (2E)
                          const float* __restrict__ vpos,   // (NB, S, E, 2)
                          ushort_t* __restrict__ krot,      // (NB,H,S,64) bf16
                          ushort_t* __restrict__ vperm)     // (NB,H,S,64) bf16
{
    __shared__ float As[64][17];
    __shared__ float Bs[64][17];
    const int t  = threadIdx.x;
    const int m0 = blockIdx.y * 64;
    const int c0 = blockIdx.x * 64;
    const int tx = t & 15, ty = t >> 4;
    const int lr = t >> 2, lc = (t & 3) * 4;
    float acc[4][4] = {};

    for (int k0 = 0; k0 < E_; k0 += 16) {
        float4 av = *reinterpret_cast<const float4*>(&A[(m0 + lr) * E_ + k0 + lc]);
        float4 bv = *reinterpret_cast<const float4*>(&W[(c0 + lr) * E_ + k0 + lc]);
        As[lr][lc + 0] = av.x; As[lr][lc + 1] = av.y; As[lr][lc + 2] = av.z; As[lr][lc + 3] = av.w;
        Bs[lr][lc + 0] = bv.x; Bs[lr][lc + 1] = bv.y; Bs[lr][lc + 2] = bv.z; Bs[lr][lc + 3] = bv.w;
        __syncthreads();
        #pragma unroll
        for (int kk = 0; kk < 16; ++kk) {
            float a[4], b[4];
            #pragma unroll
            for (int i = 0; i < 4; ++i) a[i] = As[ty * 4 + i][kk];
            #pragma unroll
            for (int j = 0; j < 4; ++j) b[j] = Bs[tx * 4 + j][kk];
            #pragma unroll
            for (int i = 0; i < 4; ++i)
                #pragma unroll
                for (int j = 0; j < 4; ++j) acc[i][j] += a[i] * b[j];
        }
        __syncthreads();
    }

    #pragma unroll
    for (int i = 0; i < 4; ++i) {
        const int m = m0 + ty * 4 + i;
        const int s = m >> 2;
        const int n = m & 3;
        const int col0 = c0 + tx * 4;
        if (col0 < E_) {  // K half: bias + rotary
            #pragma unroll
            for (int jp = 0; jp < 2; ++jp) {
                const int e0 = col0 + jp * 2;
                float v0 = acc[i][jp * 2 + 0] + bias[e0 + 0];
                float v1 = acc[i][jp * 2 + 1] + bias[e0 + 1];
                const int pb = ((n * S_ + s) * E_ + e0) * 2;
                float c0v = vpos[pb + 0], s0v = vpos[pb + 1];
                float c1v = vpos[pb + 2], s1v = vpos[pb + 3];
                float o0 = v0 * c0v - v1 * s0v;
                float o1 = v1 * c1v + v0 * s1v;
                const int hh = e0 >> 6, hd = e0 & 63;
                ushort2 ov; ov.x = f2bf(o0); ov.y = f2bf(o1);
                *(ushort2*)&krot[((n * H_ + hh) * S_ + s) * HD_ + hd] = ov;
            }
        } else {          // V half: bias only
            const int e = col0 - E_;
            const int hh = e >> 6, hd = e & 63;
            float v0 = acc[i][0] + bias[col0 + 0];
            float v1 = acc[i][1] + bias[col0 + 1];
            float v2 = acc[i][2] + bias[col0 + 2];
            float v3 = acc[i][3] + bias[col0 + 3];
            ushort4 ov;
            ov.x = f2bf(v0); ov.y = f2bf(v1); ov.z = f2bf(v2); ov.w = f2bf(v3);
            *(ushort4*)&vperm[((n * H_ + hh) * S_ + s) * HD_ + hd] = ov;
        }
    }
}

// ---------------------------------------------------------------------------
// Kernel 2b: V transpose (NB,H,S,64) -> (NB,H,64,S), bf16, LDS-tiled
// ---------------------------------------------------------------------------
__global__ __launch_bounds__(256)
void vtrans_kernel(const ushort_t* __restrict__ vin,
                   ushort_t* __restrict__ vout)
{
    __shared__ ushort_t T[64][68];
    const int t  = threadIdx.x;
    const int s0 = blockIdx.x * 64;
    const int h  = blockIdx.y, n = blockIdx.z;
    const ushort_t* src = vin + (size_t)((n * H_ + h) * S_ + s0) * HD_;
    #pragma unroll
    for (int p = 0; p < 4; ++p) {
        int e = p * 1024 + t * 4;
        int row = e >> 6, col = e & 63;
        *(ushort4*)&T[row][col] = *(const ushort4*)(src + row * HD_ + col);
    }
    __syncthreads();
    ushort_t* dst = vout + (size_t)(n * H_ + h) * HD_ * S_ + s0;
    #pragma unroll
    for (int p = 0; p < 4; ++p) {
        int d  = p * 16 + (t >> 4);
        int sc = (t & 15) * 4;
        ushort4 o;
        o.x = T[sc + 0][d]; o.y = T[sc + 1][d]; o.z = T[sc + 2][d]; o.w = T[sc + 3][d];
        *(ushort4*)(dst + (size_t)d * S_ + sc) = o;
    }
}

// ---------------------------------------------------------------------------
// Kernel 3: MFMA flash attention.
// block = 256 thr = 4 waves; wave owns 16 q-rows; block covers 64 q-rows.
// KVBLK=64 double-buffered in LDS, XOR-swizzled (row&7)<<4.
// ---------------------------------------------------------------------------
__global__ __launch_bounds__(256)
void attn_mfma_kernel(const ushort_t* __restrict__ qg,   // (NB,H,L,64) bf16
                      const ushort_t* __restrict__ kg,   // (NB,H,S,64) bf16
                      const ushort_t* __restrict__ vtg,  // (NB,H,64,S) bf16
                      float* __restrict__ ctx)           // (L, NB, E) f32
{
    __shared__ __align__(16) char smem[40960];
    char* Kb0 = smem;              // 8 KB
    char* Kb1 = smem + 8192;
    char* Vb0 = smem + 16384;
    char* Vb1 = smem + 24576;
    const int t = threadIdx.x;
    const int w = t >> 6, l = t & 63;
    char* Ps = smem + 32768 + w * 2048;   // per-wave P tile [16][64] bf16, swizzled
    const int g = l >> 4, c16 = l & 15;
    const int h = blockIdx.y, n = blockIdx.z;
    const int qb0 = blockIdx.x * 64;

    const char* kbase  = (const char*)(kg  + (size_t)(n * H_ + h) * S_ * HD_);
    const char* vtbase = (const char*)(vtg + (size_t)(n * H_ + h) * HD_ * S_);

    // Q fragments (A-operand): lane reads Q[q = c16][d = 8g..8g+7] and [32+8g..]
    const char* qrow = (const char*)(qg + (size_t)((n * H_ + h) * L_ + qb0 + w * 16 + c16) * HD_);
    s16x8 qf0 = *(const s16x8*)(qrow + 16 * g);
    s16x8 qf1 = *(const s16x8*)(qrow + 64 + 16 * g);

    // staging geometry: thread covers 2 chunks of 16B per tile
    const int srow = t >> 3;           // 0..31 (second chunk +32)
    const int scol = (t & 7) * 16;     // byte col in 128B row

    float mrun[4], lrun[4];
    f32x4 oacc[4];
    #pragma unroll
    for (int r = 0; r < 4; ++r) { mrun[r] = -1e30f; lrun[r] = 0.f; }
    #pragma unroll
    for (int s2 = 0; s2 < 4; ++s2) oacc[s2] = (f32x4){0.f, 0.f, 0.f, 0.f};

    uint4 kreg[2], vreg[2];
    #pragma unroll
    for (int c = 0; c < 2; ++c) {
        int row = c * 32 + srow;
        kreg[c] = *(const uint4*)(kbase  + (size_t)row * 128 + scol);
        vreg[c] = *(const uint4*)(vtbase + (size_t)row * (S_ * 2) + scol);
    }
    #pragma unroll
    for (int c = 0; c < 2; ++c) {
        int row = c * 32 + srow;
        int sw  = scol ^ ((row & 7) << 4);
        *(uint4*)(Kb0 + row * 128 + sw) = kreg[c];
        *(uint4*)(Vb0 + row * 128 + sw) = vreg[c];
    }
    __syncthreads();

    int cur = 0;
    for (int st = 0; st < S_ / 64; ++st) {
        if (st + 1 < S_ / 64) {   // issue next-tile global loads early (latency hides under compute)
            const char* kP = kbase  + (size_t)(st + 1) * 64 * 128;
            const char* vP = vtbase + (size_t)(st + 1) * 128;   // 64 cols * 2B
            #pragma unroll
            for (int c = 0; c < 2; ++c) {
                int row = c * 32 + srow;
                kreg[c] = *(const uint4*)(kP + (size_t)row * 128 + scol);
                vreg[c] = *(const uint4*)(vP + (size_t)row * (S_ * 2) + scol);
            }
        }
        char* K = cur ? Kb1 : Kb0;
        char* V = cur ? Vb1 : Vb0;

        // ---- QK^T: D[q][s], col=c16=s, row=4g+r=q ----
        f32x4 sacc[4];
        #pragma unroll
        for (int sub = 0; sub < 4; ++sub) {
            int row = sub * 16 + c16;
            int x = (row & 7) << 4;
            s16x8 kf0 = *(const s16x8*)(K + row * 128 + ((16 * g) ^ x));
            s16x8 kf1 = *(const s16x8*)(K + row * 128 + ((64 + 16 * g) ^ x));
            f32x4 z = (f32x4){0.f, 0.f, 0.f, 0.f};
            z = __builtin_amdgcn_mfma_f32_16x16x32_bf16(qf0, kf0, z, 0, 0, 0);
            z = __builtin_amdgcn_mfma_f32_16x16x32_bf16(qf1, kf1, z, 0, 0, 0);
            sacc[sub] = z;
        }

        // ---- online softmax (wave-parallel, shfl butterfly over 16 col-lanes) ----
        float scl[4], psum[4];
        #pragma unroll
        for (int r = 0; r < 4; ++r) {
            float m = fmaxf(fmaxf(sacc[0][r], sacc[1][r]), fmaxf(sacc[2][r], sacc[3][r]));
            #pragma unroll
            for (int msk = 1; msk < 16; msk <<= 1) m = fmaxf(m, __shfl_xor(m, msk, 64));
            float mnew = fmaxf(mrun[r], m);
            scl[r] = __expf(mrun[r] - mnew);
            mrun[r] = mnew;
            psum[r] = 0.f;
        }
        #pragma unroll
        for (int sub = 0; sub < 4; ++sub) {
            #pragma unroll
            for (int r = 0; r < 4; ++r) {
                float p = __expf(sacc[sub][r] - mrun[r]);
                psum[r] += p;
                int q = 4 * g + r;
                int by = (2 * c16 + 32 * sub) ^ ((q & 7) << 4);
                *(ushort_t*)(Ps + q * 128 + by) = f2bf(p);
            }
        }
        #pragma unroll
        for (int r = 0; r < 4; ++r) {
            float s = psum[r];
            #pragma unroll
            for (int msk = 1; msk < 16; msk <<= 1) s += __shfl_xor(s, msk, 64);
            lrun[r] = lrun[r] * scl[r] + s;
        }
        #pragma unroll
        for (int s2 = 0; s2 < 4; ++s2)
            #pragma unroll
            for (int r = 0; r < 4; ++r) oacc[s2][r] *= scl[r];

        // ---- PV: O[q][d] += P[q][s] * Vt[d][s] ----
        #pragma unroll
        for (int sh = 0; sh < 2; ++sh) {
            s16x8 pf = *(const s16x8*)(Ps + c16 * 128 + ((64 * sh + 16 * g) ^ ((c16 & 7) << 4)));
            #pragma unroll
            for (int s2 = 0; s2 < 4; ++s2) {
                int row = s2 * 16 + c16;
                int x = (row & 7) << 4;
                s16x8 vf = *(const s16x8*)(V + row * 128 + ((64 * sh + 16 * g) ^ x));
                oacc[s2] = __builtin_amdgcn_mfma_f32_16x16x32_bf16(pf, vf, oacc[s2], 0, 0, 0);
            }
        }

        if (st + 1 < S_ / 64) {
            char* Kn = cur ? Kb0 : Kb1;
            char* Vn = cur ? Vb0 : Vb1;
            #pragma unroll
            for (int c = 0; c < 2; ++c) {
                int row = c * 32 + srow;
                int sw  = scol ^ ((row & 7) << 4);
                *(uint4*)(Kn + row * 128 + sw) = kreg[c];
                *(uint4*)(Vn + row * 128 + sw) = vreg[c];
            }
            __syncthreads();
            cur ^= 1;
        }
    }

    // epilogue: O / l -> ctx (L, NB, E)
    #pragma unroll
    for (int r = 0; r < 4; ++r) {
        float inv = 1.0f / lrun[r];
        int q = qb0 + w * 16 + 4 * g + r;
        #pragma unroll
        for (int s2 = 0; s2 < 4; ++s2) {
            ctx[((size_t)q * NB + n) * E_ + h * HD_ + s2 * 16 + c16] = oacc[s2][r] * inv;
        }
    }
}

// ---------------------------------------------------------------------------
// Kernel 4: out = ctx @ Wout^T + bout + query  -> d_out (pre-LN), fp32
// ---------------------------------------------------------------------------
__global__ __launch_bounds__(256)
void outproj_kernel(const float* __restrict__ A,
                    const float* __restrict__ W,
                    const float* __restrict__ bias,
                    const float* __restrict__ resid,
                    float* __restrict__ Y)
{
    __shared__ float As[64][17];
    __shared__ float Bs[64][17];
    const int t  = threadIdx.x;
    const int m0 = blockIdx.y * 64;
    const int c0 = blockIdx.x * 64;
    const int tx = t & 15, ty = t >> 4;
    const int lr = t >> 2, lc = (t & 3) * 4;
    float acc[4][4] = {};

    for (int k0 = 0; k0 < E_; k0 += 16) {
        float4 av = *reinterpret_cast<const float4*>(&A[(m0 + lr) * E_ + k0 + lc]);
        float4 bv = *reinterpret_cast<const float4*>(&W[(c0 + lr) * E_ + k0 + lc]);
        As[lr][lc + 0] = av.x; As[lr][lc + 1] = av.y; As[lr][lc + 2] = av.z; As[lr][lc + 3] = av.w;
        Bs[lr][lc + 0] = bv.x; Bs[lr][lc + 1] = bv.y; Bs[lr][lc + 2] = bv.z; Bs[lr][lc + 3] = bv.w;
        __syncthreads();
        #pragma unroll
        for (int kk = 0; kk < 16; ++kk) {
            float a[4], b[4];
            #pragma unroll
            for (int i = 0; i < 4; ++i) a[i] = As[ty * 4 + i][kk];
            #pragma unroll
            for (int j = 0; j < 4; ++j) b[j] = Bs[tx * 4 + j][kk];
            #pragma unroll
            for (int i = 0; i < 4; ++i)
                #pragma unroll
                for (int j = 0; j < 4; ++j) acc[i][j] += a[i] * b[j];
        }
        __syncthreads();
    }

    #pragma unroll
    for (int i = 0; i < 4; ++i) {
        const int m = m0 + ty * 4 + i;
        #pragma unroll
        for (int j = 0; j < 4; ++j) {
            const int e = c0 + tx * 4 + j;
            Y[m * E_ + e] = acc[i][j] + bias[e] + resid[m * E_ + e];
        }
    }
}

// ---------------------------------------------------------------------------
// Kernel 5: in-place LayerNorm over last dim (E=512), one block per row.
// ---------------------------------------------------------------------------
__global__ __launch_bounds__(256)
void ln_kernel(float* __restrict__ y, const float* __restrict__ gamma,
               const float* __restrict__ beta)
{
    __shared__ float red1[4], red2[4];
    const int row = blockIdx.x;
    const int t   = threadIdx.x;
    float* p = y + (size_t)row * E_;
    float x0 = p[t], x1 = p[t + 256];

    float s = x0 + x1;
    #pragma unroll
    for (int o = 32; o >= 1; o >>= 1) s += __shfl_down(s, o, 64);
    if ((t & 63) == 0) red1[t >> 6] = s;
    __syncthreads();
    const float mu = (red1[0] + red1[1] + red1[2] + red1[3]) * (1.0f / E_);

    const float d0 = x0 - mu, d1 = x1 - mu;
    float vs = d0 * d0 + d1 * d1;
    #pragma unroll
    for (int o = 32; o >= 1; o >>= 1) vs += __shfl_down(vs, o, 64);
    if ((t & 63) == 0) red2[t >> 6] = vs;
    __syncthreads();
    const float var  = (red2[0] + red2[1] + red2[2] + red2[3]) * (1.0f / E_);
    const float rstd = rsqrtf(var + LNEPS);

    p[t]       = d0 * rstd * gamma[t]       + beta[t];
    p[t + 256] = d1 * rstd * gamma[t + 256] + beta[t + 256];
}

extern "C" void kernel_launch(void* const* d_in, const int* in_sizes, int n_in,
                              void* d_out, int out_size, void* d_ws, size_t ws_size,
                              hipStream_t stream) {
    const float* query = (const float*)d_in[0];
    const float* value = (const float*)d_in[1];
    const float* qpos  = (const float*)d_in[2];
    const float* vpos  = (const float*)d_in[3];
    const float* ipw   = (const float*)d_in[4];
    const float* ipb   = (const float*)d_in[5];
    const float* opw   = (const float*)d_in[6];
    const float* opb   = (const float*)d_in[7];
    const float* gamma = (const float*)d_in[8];
    const float* beta  = (const float*)d_in[9];
    float* out = (float*)d_out;

    char* ws = (char*)d_ws;
    ushort_t* qrot  = (ushort_t*)(ws);                    //  4 MB: NB*H*L*64 bf16
    ushort_t* krot  = (ushort_t*)(ws + (4u  << 20));      //  8 MB: NB*H*S*64 bf16
    ushort_t* vperm = (ushort_t*)(ws + (12u << 20));      //  8 MB: NB*H*S*64 bf16
    ushort_t* vt    = (ushort_t*)(ws + (20u << 20));      //  8 MB: NB*H*64*S bf16
    float*    ctx   = (float*)   (ws + (28u << 20));      //  8 MB: L*NB*E f32

    qproj_rotary_kernel<<<dim3(E_ / 64, (L_ * NB) / 64), 256, 0, stream>>>(
        query, ipw, ipb, qpos, qrot);
    kvproj_rotary_kernel<<<dim3((2 * E_) / 64, (S_ * NB) / 64), 256, 0, stream>>>(
        value, ipw + E_ * E_, ipb + E_, vpos, krot, vperm);
    vtrans_kernel<<<dim3(S_ / 64, H_, NB), 256, 0, stream>>>(vperm, vt);
    attn_mfma_kernel<<<dim3(L_ / 64, H_, NB), 256, 0, stream>>>(qrot, krot, vt, ctx);
    outproj_kernel<<<dim3(E_ / 64, (L_ * NB) / 64), 256, 0, stream>>>(
        ctx, opw, opb, query, out);
    ln_kernel<<<L_ * NB, 256, 0, stream>>>(out, gamma, beta);
}

// Round 5
// 287.954 us; speedup vs baseline: 5.8116x; 1.7189x over previous
//
#include <hip/hip_runtime.h>
#include <math.h>

#define L_  1024
#define S_  2048
#define NB  4
#define E_  512
#define H_  8
#define HD_ 64

constexpr float SCALING = 0.125f;   // (E/H)^-0.5 = 1/8
constexpr float LNEPS   = 1e-5f;

typedef __attribute__((ext_vector_type(8))) short s16x8;          // 8 bf16 MFMA frag
typedef __attribute__((ext_vector_type(8))) unsigned short u16x8; // 8 bf16 store
typedef __attribute__((ext_vector_type(4))) float f32x4;          // MFMA accumulator
typedef unsigned short ushort_t;

__device__ __forceinline__ unsigned short f2bf(float f) {
    unsigned u = __builtin_bit_cast(unsigned, f);
    u += 0x7fffu + ((u >> 16) & 1u);   // RNE
    return (unsigned short)(u >> 16);
}
__device__ __forceinline__ float bf2f(unsigned short h) {
    unsigned u = ((unsigned)h) << 16;
    return __builtin_bit_cast(float, u);
}

// ---------------------------------------------------------------------------
// Kernel 0: cast 4 fp32 arrays -> bf16 (query, value, ipw, opw)
// counts are cumulative 8-element chunk counts.
// ---------------------------------------------------------------------------
__global__ __launch_bounds__(256)
void cast4_kernel(const float* __restrict__ s0, const float* __restrict__ s1,
                  const float* __restrict__ s2, const float* __restrict__ s3,
                  ushort_t* __restrict__ d0, ushort_t* __restrict__ d1,
                  ushort_t* __restrict__ d2, ushort_t* __restrict__ d3,
                  int c0, int c1, int c2, int c3)
{
    int i = blockIdx.x * 256 + threadIdx.x;
    const float* s; ushort_t* d; int off;
    if      (i < c0) { s = s0; d = d0; off = i; }
    else if (i < c1) { s = s1; d = d1; off = i - c0; }
    else if (i < c2) { s = s2; d = d2; off = i - c1; }
    else if (i < c3) { s = s3; d = d3; off = i - c2; }
    else return;
    const float4* sp = (const float4*)(s + (size_t)off * 8);
    float4 a = sp[0], b = sp[1];
    u16x8 o;
    o[0] = f2bf(a.x); o[1] = f2bf(a.y); o[2] = f2bf(a.z); o[3] = f2bf(a.w);
    o[4] = f2bf(b.x); o[5] = f2bf(b.y); o[6] = f2bf(b.z); o[7] = f2bf(b.w);
    *(u16x8*)(d + (size_t)off * 8) = o;
}

// ---------------------------------------------------------------------------
// bf16 MFMA GEMM: C[token][feat] = sum_k A[token][k] * W[feat][k], K=512.
// Tile: BM = MR*32 tokens x 128 feats, BK=32. 256 thr = 4 waves (2x2).
// LDS chunk-XOR swizzle cp = c ^ ((r>>1)&3) -> <=2-way bank aliasing.
// EPI=0: write bf16 C. EPI=1: Y = acc + bias[feat] + resid (fp32, nfeat=512).
// ---------------------------------------------------------------------------
template<int MR, int EPI>
__global__ __launch_bounds__(256)
void gemm_bf16_kernel(const ushort_t* __restrict__ A,     // (Mtok, 512) bf16
                      const ushort_t* __restrict__ Bw,    // (nfeat, 512) bf16
                      ushort_t* __restrict__ Cb,          // EPI=0 out
                      const float* __restrict__ bias,     // EPI=1
                      const float* __restrict__ resid,    // EPI=1
                      float* __restrict__ Y,              // EPI=1 out
                      int nfeat)
{
    constexpr int BM = MR * 32;
    __shared__ ushort_t As[BM * 32];
    __shared__ ushort_t Bs[128 * 32];
    const int t = threadIdx.x;
    const int w = t >> 6, l = t & 63;
    const int wr = w >> 1, wc = w & 1;
    const int g = l >> 4, c16 = l & 15;
    const int m0 = blockIdx.y * BM;
    const int n0 = blockIdx.x * 128;

    f32x4 acc[MR][4];
    #pragma unroll
    for (int m = 0; m < MR; ++m)
        #pragma unroll
        for (int n = 0; n < 4; ++n) acc[m][n] = (f32x4){0.f, 0.f, 0.f, 0.f};

    for (int k0 = 0; k0 < 512; k0 += 32) {
        #pragma unroll
        for (int ch = t; ch < BM * 4; ch += 256) {
            int r = ch >> 2, c = ch & 3;
            s16x8 v = *(const s16x8*)(A + (size_t)(m0 + r) * 512 + k0 + c * 8);
            int cp = c ^ ((r >> 1) & 3);
            *(s16x8*)((char*)As + r * 64 + cp * 16) = v;
        }
        #pragma unroll
        for (int ch = t; ch < 512; ch += 256) {
            int r = ch >> 2, c = ch & 3;
            s16x8 v = *(const s16x8*)(Bw + (size_t)(n0 + r) * 512 + k0 + c * 8);
            int cp = c ^ ((r >> 1) & 3);
            *(s16x8*)((char*)Bs + r * 64 + cp * 16) = v;
        }
        __syncthreads();
        s16x8 fa[MR], fb[4];
        #pragma unroll
        for (int m = 0; m < MR; ++m) {
            int r = wr * (MR * 16) + m * 16 + c16;
            fa[m] = *(const s16x8*)((char*)As + r * 64 + ((g ^ ((r >> 1) & 3)) * 16));
        }
        #pragma unroll
        for (int n = 0; n < 4; ++n) {
            int r = wc * 64 + n * 16 + c16;
            fb[n] = *(const s16x8*)((char*)Bs + r * 64 + ((g ^ ((r >> 1) & 3)) * 16));
        }
        #pragma unroll
        for (int m = 0; m < MR; ++m)
            #pragma unroll
            for (int n = 0; n < 4; ++n)
                acc[m][n] = __builtin_amdgcn_mfma_f32_16x16x32_bf16(fa[m], fb[n], acc[m][n], 0, 0, 0);
        __syncthreads();
    }

    #pragma unroll
    for (int m = 0; m < MR; ++m) {
        #pragma unroll
        for (int n = 0; n < 4; ++n) {
            int col = n0 + wc * 64 + n * 16 + c16;
            #pragma unroll
            for (int r = 0; r < 4; ++r) {
                int row = m0 + wr * (MR * 16) + m * 16 + g * 4 + r;
                if (EPI == 0) {
                    Cb[(size_t)row * nfeat + col] = f2bf(acc[m][n][r]);
                } else {
                    float v = acc[m][n][r] + bias[col] + resid[(size_t)row * 512 + col];
                    Y[(size_t)row * 512 + col] = v;
                }
            }
        }
    }
}

// ---------------------------------------------------------------------------
// epi_q: qrot = rotary((C + bias) * scaling), bf16 scatter to (NB,H,L,64)
// one thread = 1 token x 8 consecutive features
// ---------------------------------------------------------------------------
__global__ __launch_bounds__(256)
void epi_q_kernel(const ushort_t* __restrict__ Cq,   // (4096, 512) bf16
                  const float* __restrict__ bias,    // ipb[0..512)
                  const float* __restrict__ qpos,    // (NB, L, 512, 2)
                  ushort_t* __restrict__ qrot)       // (NB,H,L,64) bf16
{
    int tid = blockIdx.x * 256 + threadIdx.x;   // 262144
    int token = tid >> 6;
    int fo = (tid & 63) * 8;
    int lq = token >> 2, n = token & 3;
    u16x8 cv = *(const u16x8*)(Cq + (size_t)token * 512 + fo);
    const float4* bp = (const float4*)(bias + fo);
    float4 b0 = bp[0], b1 = bp[1];
    float x[8];
    x[0] = (bf2f(cv[0]) + b0.x) * SCALING; x[1] = (bf2f(cv[1]) + b0.y) * SCALING;
    x[2] = (bf2f(cv[2]) + b0.z) * SCALING; x[3] = (bf2f(cv[3]) + b0.w) * SCALING;
    x[4] = (bf2f(cv[4]) + b1.x) * SCALING; x[5] = (bf2f(cv[5]) + b1.y) * SCALING;
    x[6] = (bf2f(cv[6]) + b1.z) * SCALING; x[7] = (bf2f(cv[7]) + b1.w) * SCALING;
    const float* pp = qpos + ((size_t)(n * L_ + lq) * 512 + fo) * 2;  // 16 floats
    u16x8 o;
    #pragma unroll
    for (int jp = 0; jp < 4; ++jp) {
        float4 p = *(const float4*)(pp + jp * 4);  // cos0,sin0,cos1,sin1
        float v0 = x[2 * jp], v1 = x[2 * jp + 1];
        o[2 * jp]     = f2bf(v0 * p.x - v1 * p.y);
        o[2 * jp + 1] = f2bf(v1 * p.z + v0 * p.w);
    }
    int h = fo >> 6, hd = fo & 63;
    *(u16x8*)(qrot + ((size_t)((n * H_ + h) * L_ + lq)) * HD_ + hd) = o;
}

// ---------------------------------------------------------------------------
// epi_kv: feats<512 -> K (+bias,+rotary) -> krot; >=512 -> V (+bias) -> vperm
// ---------------------------------------------------------------------------
__global__ __launch_bounds__(256)
void epi_kv_kernel(const ushort_t* __restrict__ Ckv,  // (8192, 1024) bf16
                   const float* __restrict__ bias,    // ipb+512 (1024)
                   const float* __restrict__ vpos,    // (NB, S, 512, 2)
                   ushort_t* __restrict__ krot,       // (NB,H,S,64) bf16
                   ushort_t* __restrict__ vperm)      // (NB,H,S,64) bf16
{
    int tid = blockIdx.x * 256 + threadIdx.x;   // 1048576
    int token = tid >> 7;
    int fo = (tid & 127) * 8;
    int s = token >> 2, n = token & 3;
    u16x8 cv = *(const u16x8*)(Ckv + (size_t)token * 1024 + fo);
    const float4* bp = (const float4*)(bias + fo);
    float4 b0 = bp[0], b1 = bp[1];
    float x[8];
    x[0] = bf2f(cv[0]) + b0.x; x[1] = bf2f(cv[1]) + b0.y;
    x[2] = bf2f(cv[2]) + b0.z; x[3] = bf2f(cv[3]) + b0.w;
    x[4] = bf2f(cv[4]) + b1.x; x[5] = bf2f(cv[5]) + b1.y;
    x[6] = bf2f(cv[6]) + b1.z; x[7] = bf2f(cv[7]) + b1.w;
    u16x8 o;
    if (fo < 512) {  // K + rotary
        const float* pp = vpos + ((size_t)(n * S_ + s) * 512 + fo) * 2;
        #pragma unroll
        for (int jp = 0; jp < 4; ++jp) {
            float4 p = *(const float4*)(pp + jp * 4);
            float v0 = x[2 * jp], v1 = x[2 * jp + 1];
            o[2 * jp]     = f2bf(v0 * p.x - v1 * p.y);
            o[2 * jp + 1] = f2bf(v1 * p.z + v0 * p.w);
        }
        int h = fo >> 6, hd = fo & 63;
        *(u16x8*)(krot + ((size_t)((n * H_ + h) * S_ + s)) * HD_ + hd) = o;
    } else {         // V
        #pragma unroll
        for (int j = 0; j < 8; ++j) o[j] = f2bf(x[j]);
        int f = fo - 512;
        int h = f >> 6, hd = f & 63;
        *(u16x8*)(vperm + ((size_t)((n * H_ + h) * S_ + s)) * HD_ + hd) = o;
    }
}

// ---------------------------------------------------------------------------
// V transpose (NB,H,S,64) -> (NB,H,64,S), bf16, LDS-tiled
// ---------------------------------------------------------------------------
__global__ __launch_bounds__(256)
void vtrans_kernel(const ushort_t* __restrict__ vin,
                   ushort_t* __restrict__ vout)
{
    __shared__ ushort_t T[64][68];
    const int t  = threadIdx.x;
    const int s0 = blockIdx.x * 64;
    const int h  = blockIdx.y, n = blockIdx.z;
    const ushort_t* src = vin + (size_t)((n * H_ + h) * S_ + s0) * HD_;
    #pragma unroll
    for (int p = 0; p < 4; ++p) {
        int e = p * 1024 + t * 4;
        int row = e >> 6, col = e & 63;
        *(ushort4*)&T[row][col] = *(const ushort4*)(src + row * HD_ + col);
    }
    __syncthreads();
    ushort_t* dst = vout + (size_t)(n * H_ + h) * HD_ * S_ + s0;
    #pragma unroll
    for (int p = 0; p < 4; ++p) {
        int d  = p * 16 + (t >> 4);
        int sc = (t & 15) * 4;
        ushort4 o;
        o.x = T[sc + 0][d]; o.y = T[sc + 1][d]; o.z = T[sc + 2][d]; o.w = T[sc + 3][d];
        *(ushort4*)(dst + (size_t)d * S_ + sc) = o;
    }
}

// ---------------------------------------------------------------------------
// MFMA flash attention (as round 4), ctx out as bf16.
// ---------------------------------------------------------------------------
__global__ __launch_bounds__(256)
void attn_mfma_kernel(const ushort_t* __restrict__ qg,   // (NB,H,L,64) bf16
                      const ushort_t* __restrict__ kg,   // (NB,H,S,64) bf16
                      const ushort_t* __restrict__ vtg,  // (NB,H,64,S) bf16
                      ushort_t* __restrict__ ctxb)       // (L, NB, E) bf16
{
    __shared__ __align__(16) char smem[40960];
    char* Kb0 = smem;
    char* Kb1 = smem + 8192;
    char* Vb0 = smem + 16384;
    char* Vb1 = smem + 24576;
    const int t = threadIdx.x;
    const int w = t >> 6, l = t & 63;
    char* Ps = smem + 32768 + w * 2048;
    const int g = l >> 4, c16 = l & 15;
    const int h = blockIdx.y, n = blockIdx.z;
    const int qb0 = blockIdx.x * 64;

    const char* kbase  = (const char*)(kg  + (size_t)(n * H_ + h) * S_ * HD_);
    const char* vtbase = (const char*)(vtg + (size_t)(n * H_ + h) * HD_ * S_);

    const char* qrow = (const char*)(qg + (size_t)((n * H_ + h) * L_ + qb0 + w * 16 + c16) * HD_);
    s16x8 qf0 = *(const s16x8*)(qrow + 16 * g);
    s16x8 qf1 = *(const s16x8*)(qrow + 64 + 16 * g);

    const int srow = t >> 3;
    const int scol = (t & 7) * 16;

    float mrun[4], lrun[4];
    f32x4 oacc[4];
    #pragma unroll
    for (int r = 0; r < 4; ++r) { mrun[r] = -1e30f; lrun[r] = 0.f; }
    #pragma unroll
    for (int s2 = 0; s2 < 4; ++s2) oacc[s2] = (f32x4){0.f, 0.f, 0.f, 0.f};

    uint4 kreg[2], vreg[2];
    #pragma unroll
    for (int c = 0; c < 2; ++c) {
        int row = c * 32 + srow;
        kreg[c] = *(const uint4*)(kbase  + (size_t)row * 128 + scol);
        vreg[c] = *(const uint4*)(vtbase + (size_t)row * (S_ * 2) + scol);
    }
    #pragma unroll
    for (int c = 0; c < 2; ++c) {
        int row = c * 32 + srow;
        int sw  = scol ^ ((row & 7) << 4);
        *(uint4*)(Kb0 + row * 128 + sw) = kreg[c];
        *(uint4*)(Vb0 + row * 128 + sw) = vreg[c];
    }
    __syncthreads();

    int cur = 0;
    for (int st = 0; st < S_ / 64; ++st) {
        if (st + 1 < S_ / 64) {
            const char* kP = kbase  + (size_t)(st + 1) * 64 * 128;
            const char* vP = vtbase + (size_t)(st + 1) * 128;
            #pragma unroll
            for (int c = 0; c < 2; ++c) {
                int row = c * 32 + srow;
                kreg[c] = *(const uint4*)(kP + (size_t)row * 128 + scol);
                vreg[c] = *(const uint4*)(vP + (size_t)row * (S_ * 2) + scol);
            }
        }
        char* K = cur ? Kb1 : Kb0;
        char* V = cur ? Vb1 : Vb0;

        f32x4 sacc[4];
        #pragma unroll
        for (int sub = 0; sub < 4; ++sub) {
            int row = sub * 16 + c16;
            int x = (row & 7) << 4;
            s16x8 kf0 = *(const s16x8*)(K + row * 128 + ((16 * g) ^ x));
            s16x8 kf1 = *(const s16x8*)(K + row * 128 + ((64 + 16 * g) ^ x));
            f32x4 z = (f32x4){0.f, 0.f, 0.f, 0.f};
            z = __builtin_amdgcn_mfma_f32_16x16x32_bf16(qf0, kf0, z, 0, 0, 0);
            z = __builtin_amdgcn_mfma_f32_16x16x32_bf16(qf1, kf1, z, 0, 0, 0);
            sacc[sub] = z;
        }

        float scl[4], psum[4];
        #pragma unroll
        for (int r = 0; r < 4; ++r) {
            float m = fmaxf(fmaxf(sacc[0][r], sacc[1][r]), fmaxf(sacc[2][r], sacc[3][r]));
            #pragma unroll
            for (int msk = 1; msk < 16; msk <<= 1) m = fmaxf(m, __shfl_xor(m, msk, 64));
            float mnew = fmaxf(mrun[r], m);
            scl[r] = __expf(mrun[r] - mnew);
            mrun[r] = mnew;
            psum[r] = 0.f;
        }
        #pragma unroll
        for (int sub = 0; sub < 4; ++sub) {
            #pragma unroll
            for (int r = 0; r < 4; ++r) {
                float p = __expf(sacc[sub][r] - mrun[r]);
                psum[r] += p;
                int q = 4 * g + r;
                int by = (2 * c16 + 32 * sub) ^ ((q & 7) << 4);
                *(ushort_t*)(Ps + q * 128 + by) = f2bf(p);
            }
        }
        #pragma unroll
        for (int r = 0; r < 4; ++r) {
            float s = psum[r];
            #pragma unroll
            for (int msk = 1; msk < 16; msk <<= 1) s += __shfl_xor(s, msk, 64);
            lrun[r] = lrun[r] * scl[r] + s;
        }
        #pragma unroll
        for (int s2 = 0; s2 < 4; ++s2)
            #pragma unroll
            for (int r = 0; r < 4; ++r) oacc[s2][r] *= scl[r];

        #pragma unroll
        for (int sh = 0; sh < 2; ++sh) {
            s16x8 pf = *(const s16x8*)(Ps + c16 * 128 + ((64 * sh + 16 * g) ^ ((c16 & 7) << 4)));
            #pragma unroll
            for (int s2 = 0; s2 < 4; ++s2) {
                int row = s2 * 16 + c16;
                int x = (row & 7) << 4;
                s16x8 vf = *(const s16x8*)(V + row * 128 + ((64 * sh + 16 * g) ^ x));
                oacc[s2] = __builtin_amdgcn_mfma_f32_16x16x32_bf16(pf, vf, oacc[s2], 0, 0, 0);
            }
        }

        if (st + 1 < S_ / 64) {
            char* Kn = cur ? Kb0 : Kb1;
            char* Vn = cur ? Vb0 : Vb1;
            #pragma unroll
            for (int c = 0; c < 2; ++c) {
                int row = c * 32 + srow;
                int sw  = scol ^ ((row & 7) << 4);
                *(uint4*)(Kn + row * 128 + sw) = kreg[c];
                *(uint4*)(Vn + row * 128 + sw) = vreg[c];
            }
            __syncthreads();
            cur ^= 1;
        }
    }

    #pragma unroll
    for (int r = 0; r < 4; ++r) {
        float inv = 1.0f / lrun[r];
        int q = qb0 + w * 16 + 4 * g + r;
        #pragma unroll
        for (int s2 = 0; s2 < 4; ++s2) {
            ctxb[((size_t)q * NB + n) * E_ + h * HD_ + s2 * 16 + c16] = f2bf(oacc[s2][r] * inv);
        }
    }
}

// ---------------------------------------------------------------------------
// LayerNorm in-place (E=512), one block per row.
// ---------------------------------------------------------------------------
__global__ __launch_bounds__(256)
void ln_kernel(float* __restrict__ y, const float* __restrict__ gamma,
               const float* __restrict__ beta)
{
    __shared__ float red1[4], red2[4];
    const int row = blockIdx.x;
    const int t   = threadIdx.x;
    float* p = y + (size_t)row * E_;
    float x0 = p[t], x1 = p[t + 256];

    float s = x0 + x1;
    #pragma unroll
    for (int o = 32; o >= 1; o >>= 1) s += __shfl_down(s, o, 64);
    if ((t & 63) == 0) red1[t >> 6] = s;
    __syncthreads();
    const float mu = (red1[0] + red1[1] + red1[2] + red1[3]) * (1.0f / E_);

    const float d0 = x0 - mu, d1 = x1 - mu;
    float vs = d0 * d0 + d1 * d1;
    #pragma unroll
    for (int o = 32; o >= 1; o >>= 1) vs += __shfl_down(vs, o, 64);
    if ((t & 63) == 0) red2[t >> 6] = vs;
    __syncthreads();
    const float var  = (red2[0] + red2[1] + red2[2] + red2[3]) * (1.0f / E_);
    const float rstd = rsqrtf(var + LNEPS);

    p[t]       = d0 * rstd * gamma[t]       + beta[t];
    p[t + 256] = d1 * rstd * gamma[t + 256] + beta[t + 256];
}

extern "C" void kernel_launch(void* const* d_in, const int* in_sizes, int n_in,
                              void* d_out, int out_size, void* d_ws, size_t ws_size,
                              hipStream_t stream) {
    const float* query = (const float*)d_in[0];
    const float* value = (const float*)d_in[1];
    const float* qpos  = (const float*)d_in[2];
    const float* vpos  = (const float*)d_in[3];
    const float* ipw   = (const float*)d_in[4];
    const float* ipb   = (const float*)d_in[5];
    const float* opw   = (const float*)d_in[6];
    const float* opb   = (const float*)d_in[7];
    const float* gamma = (const float*)d_in[8];
    const float* beta  = (const float*)d_in[9];
    float* out = (float*)d_out;

    char* ws = (char*)d_ws;
    ushort_t* kvC   = (ushort_t*)(ws);                    // [0,16) MB : 8192x1024 bf16
    ushort_t* vbf   = (ushort_t*)(ws + (16u << 20));      // [16,24): 8192x512
    ushort_t* qbf   = (ushort_t*)(ws + (24u << 20));      // [24,28): 4096x512
    ushort_t* wbf   = (ushort_t*)(ws + (28u << 20));      // [28,29.5): 1536x512 (ipw)
    ushort_t* obf   = (ushort_t*)(ws + (30u << 20));      // [30,30.5): 512x512 (opw)
    ushort_t* qC    = (ushort_t*)(ws + (31u << 20));      // [31,35): 4096x512
    ushort_t* qrot  = (ushort_t*)(ws + (35u << 20));      // [35,39): NB*H*L*64
    ushort_t* krot  = (ushort_t*)(ws + (39u << 20));      // [39,47): NB*H*S*64
    ushort_t* vperm = (ushort_t*)(ws + (47u << 20));      // [47,55): NB*H*S*64
    ushort_t* vt    = (ushort_t*)(ws);                    // [0,8)  : reuse kvC (dead)
    ushort_t* ctxb  = (ushort_t*)(ws + (8u << 20));       // [8,12) : reuse kvC (dead)

    // cumulative 8-elem chunk counts: query 2M, value 4M, ipw 786432, opw 262144
    const int c0 = 262144;
    const int c1 = c0 + 524288;
    const int c2 = c1 + 98304;
    const int c3 = c2 + 32768;
    cast4_kernel<<<3584, 256, 0, stream>>>(query, value, ipw, opw,
                                           qbf, vbf, wbf, obf, c0, c1, c2, c3);

    // q GEMM: (4096 x 512) x (512 x 512)^T -> qC bf16
    gemm_bf16_kernel<2, 0><<<dim3(512 / 128, 4096 / 64), 256, 0, stream>>>(
        qbf, wbf, qC, nullptr, nullptr, nullptr, 512);
    // kv GEMM: (8192 x 512) x (1024 x 512)^T -> kvC bf16
    gemm_bf16_kernel<4, 0><<<dim3(1024 / 128, 8192 / 128), 256, 0, stream>>>(
        vbf, wbf + (size_t)E_ * E_, kvC, nullptr, nullptr, nullptr, 1024);

    epi_q_kernel<<<1024, 256, 0, stream>>>(qC, ipb, qpos, qrot);
    epi_kv_kernel<<<4096, 256, 0, stream>>>(kvC, ipb + E_, vpos, krot, vperm);

    vtrans_kernel<<<dim3(S_ / 64, H_, NB), 256, 0, stream>>>(vperm, vt);
    attn_mfma_kernel<<<dim3(L_ / 64, H_, NB), 256, 0, stream>>>(qrot, krot, vt, ctxb);

    // out GEMM fused: Y = ctx @ Wout^T + bout + query
    gemm_bf16_kernel<2, 1><<<dim3(512 / 128, 4096 / 64), 256, 0, stream>>>(
        ctxb, obf, nullptr, opb, query, out, 512);

    ln_kernel<<<L_ * NB, 256, 0, stream>>>(out, gamma, beta);
}

// Round 6
// 252.579 us; speedup vs baseline: 6.6255x; 1.1401x over previous
//
#include <hip/hip_runtime.h>
#include <math.h>

#define L_  1024
#define S_  2048
#define NB  4
#define E_  512
#define H_  8
#define HD_ 64
#define SPLIT 2

constexpr float SCALING = 0.125f;   // (E/H)^-0.5 = 1/8
constexpr float LNEPS   = 1e-5f;

typedef __attribute__((ext_vector_type(8))) short s16x8;          // 8 bf16 MFMA frag
typedef __attribute__((ext_vector_type(8))) unsigned short u16x8; // 8 bf16 store
typedef __attribute__((ext_vector_type(4))) float f32x4;          // MFMA accumulator
typedef unsigned short ushort_t;

__device__ __forceinline__ unsigned short f2bf(float f) {
    unsigned u = __builtin_bit_cast(unsigned, f);
    u += 0x7fffu + ((u >> 16) & 1u);   // RNE
    return (unsigned short)(u >> 16);
}
__device__ __forceinline__ float bf2f(unsigned short h) {
    unsigned u = ((unsigned)h) << 16;
    return __builtin_bit_cast(float, u);
}
__device__ __forceinline__ unsigned packbf(float a, float b) {
    return (unsigned)f2bf(a) | ((unsigned)f2bf(b) << 16);
}

// ---------------------------------------------------------------------------
// Kernel 0: cast 4 fp32 arrays -> bf16 (query, value, ipw, opw)
// ---------------------------------------------------------------------------
__global__ __launch_bounds__(256)
void cast4_kernel(const float* __restrict__ s0, const float* __restrict__ s1,
                  const float* __restrict__ s2, const float* __restrict__ s3,
                  ushort_t* __restrict__ d0, ushort_t* __restrict__ d1,
                  ushort_t* __restrict__ d2, ushort_t* __restrict__ d3,
                  int c0, int c1, int c2, int c3)
{
    int i = blockIdx.x * 256 + threadIdx.x;
    const float* s; ushort_t* d; int off;
    if      (i < c0) { s = s0; d = d0; off = i; }
    else if (i < c1) { s = s1; d = d1; off = i - c0; }
    else if (i < c2) { s = s2; d = d2; off = i - c1; }
    else if (i < c3) { s = s3; d = d3; off = i - c2; }
    else return;
    const float4* sp = (const float4*)(s + (size_t)off * 8);
    float4 a = sp[0], b = sp[1];
    u16x8 o;
    o[0] = f2bf(a.x); o[1] = f2bf(a.y); o[2] = f2bf(a.z); o[3] = f2bf(a.w);
    o[4] = f2bf(b.x); o[5] = f2bf(b.y); o[6] = f2bf(b.z); o[7] = f2bf(b.w);
    *(u16x8*)(d + (size_t)off * 8) = o;
}

// ---------------------------------------------------------------------------
// bf16 MFMA GEMM (unchanged from R5)
// ---------------------------------------------------------------------------
template<int MR, int EPI>
__global__ __launch_bounds__(256)
void gemm_bf16_kernel(const ushort_t* __restrict__ A,
                      const ushort_t* __restrict__ Bw,
                      ushort_t* __restrict__ Cb,
                      const float* __restrict__ bias,
                      const float* __restrict__ resid,
                      float* __restrict__ Y,
                      int nfeat)
{
    constexpr int BM = MR * 32;
    __shared__ ushort_t As[BM * 32];
    __shared__ ushort_t Bs[128 * 32];
    const int t = threadIdx.x;
    const int w = t >> 6, l = t & 63;
    const int wr = w >> 1, wc = w & 1;
    const int g = l >> 4, c16 = l & 15;
    const int m0 = blockIdx.y * BM;
    const int n0 = blockIdx.x * 128;

    f32x4 acc[MR][4];
    #pragma unroll
    for (int m = 0; m < MR; ++m)
        #pragma unroll
        for (int n = 0; n < 4; ++n) acc[m][n] = (f32x4){0.f, 0.f, 0.f, 0.f};

    for (int k0 = 0; k0 < 512; k0 += 32) {
        #pragma unroll
        for (int ch = t; ch < BM * 4; ch += 256) {
            int r = ch >> 2, c = ch & 3;
            s16x8 v = *(const s16x8*)(A + (size_t)(m0 + r) * 512 + k0 + c * 8);
            int cp = c ^ ((r >> 1) & 3);
            *(s16x8*)((char*)As + r * 64 + cp * 16) = v;
        }
        #pragma unroll
        for (int ch = t; ch < 512; ch += 256) {
            int r = ch >> 2, c = ch & 3;
            s16x8 v = *(const s16x8*)(Bw + (size_t)(n0 + r) * 512 + k0 + c * 8);
            int cp = c ^ ((r >> 1) & 3);
            *(s16x8*)((char*)Bs + r * 64 + cp * 16) = v;
        }
        __syncthreads();
        s16x8 fa[MR], fb[4];
        #pragma unroll
        for (int m = 0; m < MR; ++m) {
            int r = wr * (MR * 16) + m * 16 + c16;
            fa[m] = *(const s16x8*)((char*)As + r * 64 + ((g ^ ((r >> 1) & 3)) * 16));
        }
        #pragma unroll
        for (int n = 0; n < 4; ++n) {
            int r = wc * 64 + n * 16 + c16;
            fb[n] = *(const s16x8*)((char*)Bs + r * 64 + ((g ^ ((r >> 1) & 3)) * 16));
        }
        #pragma unroll
        for (int m = 0; m < MR; ++m)
            #pragma unroll
            for (int n = 0; n < 4; ++n)
                acc[m][n] = __builtin_amdgcn_mfma_f32_16x16x32_bf16(fa[m], fb[n], acc[m][n], 0, 0, 0);
        __syncthreads();
    }

    #pragma unroll
    for (int m = 0; m < MR; ++m) {
        #pragma unroll
        for (int n = 0; n < 4; ++n) {
            int col = n0 + wc * 64 + n * 16 + c16;
            #pragma unroll
            for (int r = 0; r < 4; ++r) {
                int row = m0 + wr * (MR * 16) + m * 16 + g * 4 + r;
                if (EPI == 0) {
                    Cb[(size_t)row * nfeat + col] = f2bf(acc[m][n][r]);
                } else {
                    float v = acc[m][n][r] + bias[col] + resid[(size_t)row * 512 + col];
                    Y[(size_t)row * 512 + col] = v;
                }
            }
        }
    }
}

// ---------------------------------------------------------------------------
// epi_q / epi_kv (unchanged from R5)
// ---------------------------------------------------------------------------
__global__ __launch_bounds__(256)
void epi_q_kernel(const ushort_t* __restrict__ Cq,
                  const float* __restrict__ bias,
                  const float* __restrict__ qpos,
                  ushort_t* __restrict__ qrot)
{
    int tid = blockIdx.x * 256 + threadIdx.x;
    int token = tid >> 6;
    int fo = (tid & 63) * 8;
    int lq = token >> 2, n = token & 3;
    u16x8 cv = *(const u16x8*)(Cq + (size_t)token * 512 + fo);
    const float4* bp = (const float4*)(bias + fo);
    float4 b0 = bp[0], b1 = bp[1];
    float x[8];
    x[0] = (bf2f(cv[0]) + b0.x) * SCALING; x[1] = (bf2f(cv[1]) + b0.y) * SCALING;
    x[2] = (bf2f(cv[2]) + b0.z) * SCALING; x[3] = (bf2f(cv[3]) + b0.w) * SCALING;
    x[4] = (bf2f(cv[4]) + b1.x) * SCALING; x[5] = (bf2f(cv[5]) + b1.y) * SCALING;
    x[6] = (bf2f(cv[6]) + b1.z) * SCALING; x[7] = (bf2f(cv[7]) + b1.w) * SCALING;
    const float* pp = qpos + ((size_t)(n * L_ + lq) * 512 + fo) * 2;
    u16x8 o;
    #pragma unroll
    for (int jp = 0; jp < 4; ++jp) {
        float4 p = *(const float4*)(pp + jp * 4);
        float v0 = x[2 * jp], v1 = x[2 * jp + 1];
        o[2 * jp]     = f2bf(v0 * p.x - v1 * p.y);
        o[2 * jp + 1] = f2bf(v1 * p.z + v0 * p.w);
    }
    int h = fo >> 6, hd = fo & 63;
    *(u16x8*)(qrot + ((size_t)((n * H_ + h) * L_ + lq)) * HD_ + hd) = o;
}

__global__ __launch_bounds__(256)
void epi_kv_kernel(const ushort_t* __restrict__ Ckv,
                   const float* __restrict__ bias,
                   const float* __restrict__ vpos,
                   ushort_t* __restrict__ krot,
                   ushort_t* __restrict__ vperm)
{
    int tid = blockIdx.x * 256 + threadIdx.x;
    int token = tid >> 7;
    int fo = (tid & 127) * 8;
    int s = token >> 2, n = token & 3;
    u16x8 cv = *(const u16x8*)(Ckv + (size_t)token * 1024 + fo);
    const float4* bp = (const float4*)(bias + fo);
    float4 b0 = bp[0], b1 = bp[1];
    float x[8];
    x[0] = bf2f(cv[0]) + b0.x; x[1] = bf2f(cv[1]) + b0.y;
    x[2] = bf2f(cv[2]) + b0.z; x[3] = bf2f(cv[3]) + b0.w;
    x[4] = bf2f(cv[4]) + b1.x; x[5] = bf2f(cv[5]) + b1.y;
    x[6] = bf2f(cv[6]) + b1.z; x[7] = bf2f(cv[7]) + b1.w;
    u16x8 o;
    if (fo < 512) {
        const float* pp = vpos + ((size_t)(n * S_ + s) * 512 + fo) * 2;
        #pragma unroll
        for (int jp = 0; jp < 4; ++jp) {
            float4 p = *(const float4*)(pp + jp * 4);
            float v0 = x[2 * jp], v1 = x[2 * jp + 1];
            o[2 * jp]     = f2bf(v0 * p.x - v1 * p.y);
            o[2 * jp + 1] = f2bf(v1 * p.z + v0 * p.w);
        }
        int h = fo >> 6, hd = fo & 63;
        *(u16x8*)(krot + ((size_t)((n * H_ + h) * S_ + s)) * HD_ + hd) = o;
    } else {
        #pragma unroll
        for (int j = 0; j < 8; ++j) o[j] = f2bf(x[j]);
        int f = fo - 512;
        int h = f >> 6, hd = f & 63;
        *(u16x8*)(vperm + ((size_t)((n * H_ + h) * S_ + s)) * HD_ + hd) = o;
    }
}

// ---------------------------------------------------------------------------
// V transpose (unchanged)
// ---------------------------------------------------------------------------
__global__ __launch_bounds__(256)
void vtrans_kernel(const ushort_t* __restrict__ vin,
                   ushort_t* __restrict__ vout)
{
    __shared__ ushort_t T[64][68];
    const int t  = threadIdx.x;
    const int s0 = blockIdx.x * 64;
    const int h  = blockIdx.y, n = blockIdx.z;
    const ushort_t* src = vin + (size_t)((n * H_ + h) * S_ + s0) * HD_;
    #pragma unroll
    for (int p = 0; p < 4; ++p) {
        int e = p * 1024 + t * 4;
        int row = e >> 6, col = e & 63;
        *(ushort4*)&T[row][col] = *(const ushort4*)(src + row * HD_ + col);
    }
    __syncthreads();
    ushort_t* dst = vout + (size_t)(n * H_ + h) * HD_ * S_ + s0;
    #pragma unroll
    for (int p = 0; p < 4; ++p) {
        int d  = p * 16 + (t >> 4);
        int sc = (t & 15) * 4;
        ushort4 o;
        o.x = T[sc + 0][d]; o.y = T[sc + 1][d]; o.z = T[sc + 2][d]; o.w = T[sc + 3][d];
        *(ushort4*)(dst + (size_t)d * S_ + sc) = o;
    }
}

// ---------------------------------------------------------------------------
// MFMA flash attention, swapped-operand QK^T + S-split partials.
// z = n*SPLIT + sp; block covers 64 q-rows x S/SPLIT keys.
// Outputs UNNORMALIZED O (f32) + per-(q,n,h) running (m,l).
// ---------------------------------------------------------------------------
__global__ __launch_bounds__(256)
void attn_mfma_kernel(const ushort_t* __restrict__ qg,   // (NB,H,L,64) bf16
                      const ushort_t* __restrict__ kg,   // (NB,H,S,64) bf16
                      const ushort_t* __restrict__ vtg,  // (NB,H,64,S) bf16
                      float* __restrict__ pctx,          // [SPLIT][L*NB*E] f32
                      float2* __restrict__ pml)          // [SPLIT][NB][H][L]
{
    __shared__ __align__(16) char smem[40960];
    char* Kb0 = smem;
    char* Kb1 = smem + 8192;
    char* Vb0 = smem + 16384;
    char* Vb1 = smem + 24576;
    const int t = threadIdx.x;
    const int w = t >> 6, l = t & 63;
    char* Ps = smem + 32768 + w * 2048;     // per-wave P [16 q][64 s] bf16, swizzled
    const int g = l >> 4, c16 = l & 15;
    const int h = blockIdx.y;
    const int n = blockIdx.z / SPLIT, sp = blockIdx.z % SPLIT;
    const int qb0 = blockIdx.x * 64;
    constexpr int NT = (S_ / SPLIT) / 64;   // tiles per block

    const char* kbase  = (const char*)(kg  + (size_t)(n * H_ + h) * S_ * HD_)
                       + (size_t)sp * (S_ / SPLIT) * 128;
    const char* vtbase = (const char*)(vtg + (size_t)(n * H_ + h) * HD_ * S_)
                       + (size_t)sp * (S_ / SPLIT) * 2;

    // Q fragment (B-operand): lane holds Q[q=c16][d=8g..8g+7], [32+8g..]
    const int qgl = qb0 + w * 16 + c16;     // this lane's q row
    const char* qrow = (const char*)(qg + (size_t)((n * H_ + h) * L_ + qgl) * HD_);
    s16x8 qf0 = *(const s16x8*)(qrow + 16 * g);
    s16x8 qf1 = *(const s16x8*)(qrow + 64 + 16 * g);

    const int srow = t >> 3;
    const int scol = (t & 7) * 16;

    float mrun = -1e30f, lrun = 0.f;
    f32x4 oacc[4];
    #pragma unroll
    for (int s2 = 0; s2 < 4; ++s2) oacc[s2] = (f32x4){0.f, 0.f, 0.f, 0.f};

    uint4 kreg[2], vreg[2];
    #pragma unroll
    for (int c = 0; c < 2; ++c) {
        int row = c * 32 + srow;
        kreg[c] = *(const uint4*)(kbase  + (size_t)row * 128 + scol);
        vreg[c] = *(const uint4*)(vtbase + (size_t)row * (S_ * 2) + scol);
    }
    #pragma unroll
    for (int c = 0; c < 2; ++c) {
        int row = c * 32 + srow;
        int sw  = scol ^ ((row & 7) << 4);
        *(uint4*)(Kb0 + row * 128 + sw) = kreg[c];
        *(uint4*)(Vb0 + row * 128 + sw) = vreg[c];
    }
    __syncthreads();

    int cur = 0;
    for (int st = 0; st < NT; ++st) {
        if (st + 1 < NT) {
            const char* kP = kbase  + (size_t)(st + 1) * 64 * 128;
            const char* vP = vtbase + (size_t)(st + 1) * 128;
            #pragma unroll
            for (int c = 0; c < 2; ++c) {
                int row = c * 32 + srow;
                kreg[c] = *(const uint4*)(kP + (size_t)row * 128 + scol);
                vreg[c] = *(const uint4*)(vP + (size_t)row * (S_ * 2) + scol);
            }
        }
        char* K = cur ? Kb1 : Kb0;
        char* V = cur ? Vb1 : Vb0;

        // ---- QK^T swapped: D[s][q]; col=c16=q, row=4g+r=s (within subtile) ----
        f32x4 sacc[4];
        #pragma unroll
        for (int sub = 0; sub < 4; ++sub) {
            int row = sub * 16 + c16;
            int x = (row & 7) << 4;
            s16x8 kf0 = *(const s16x8*)(K + row * 128 + ((16 * g) ^ x));
            s16x8 kf1 = *(const s16x8*)(K + row * 128 + ((64 + 16 * g) ^ x));
            f32x4 z = (f32x4){0.f, 0.f, 0.f, 0.f};
            z = __builtin_amdgcn_mfma_f32_16x16x32_bf16(kf0, qf0, z, 0, 0, 0);
            z = __builtin_amdgcn_mfma_f32_16x16x32_bf16(kf1, qf1, z, 0, 0, 0);
            sacc[sub] = z;   // sacc[sub][r] = S[q=c16][s = 16*sub + 4*g + r]
        }

        // ---- softmax: lane owns 16 S-values of q=c16; reduce across g ----
        float mloc = sacc[0][0];
        #pragma unroll
        for (int sub = 0; sub < 4; ++sub)
            #pragma unroll
            for (int r = 0; r < 4; ++r) mloc = fmaxf(mloc, sacc[sub][r]);
        mloc = fmaxf(mloc, __shfl_xor(mloc, 16, 64));
        mloc = fmaxf(mloc, __shfl_xor(mloc, 32, 64));
        float mnew = fmaxf(mrun, mloc);
        float scl = __expf(mrun - mnew);
        mrun = mnew;

        float p[4][4];
        float ps = 0.f;
        #pragma unroll
        for (int sub = 0; sub < 4; ++sub)
            #pragma unroll
            for (int r = 0; r < 4; ++r) {
                float e = __expf(sacc[sub][r] - mnew);
                p[sub][r] = e;
                ps += e;
            }
        ps += __shfl_xor(ps, 16, 64);
        ps += __shfl_xor(ps, 32, 64);
        lrun = lrun * scl + ps;

        // ---- P -> LDS: lane-local packed b64 writes (4 per lane) ----
        #pragma unroll
        for (int sub = 0; sub < 4; ++sub) {
            uint2 pk;
            pk.x = packbf(p[sub][0], p[sub][1]);
            pk.y = packbf(p[sub][2], p[sub][3]);
            int by = (32 * sub + 8 * g) ^ ((c16 & 7) << 4);
            *(uint2*)(Ps + c16 * 128 + by) = pk;
        }

        // ---- rescale O: need scl of q = 4g+r ----
        float sclr[4];
        #pragma unroll
        for (int r = 0; r < 4; ++r) sclr[r] = __shfl(scl, 4 * g + r, 16);
        #pragma unroll
        for (int s2 = 0; s2 < 4; ++s2)
            #pragma unroll
            for (int r = 0; r < 4; ++r) oacc[s2][r] *= sclr[r];

        // ---- PV: O[q][d] += P[q][s] * Vt[d][s] ----
        #pragma unroll
        for (int sh = 0; sh < 2; ++sh) {
            s16x8 pf = *(const s16x8*)(Ps + c16 * 128 + ((64 * sh + 16 * g) ^ ((c16 & 7) << 4)));
            #pragma unroll
            for (int s2 = 0; s2 < 4; ++s2) {
                int row = s2 * 16 + c16;
                int x = (row & 7) << 4;
                s16x8 vf = *(const s16x8*)(V + row * 128 + ((64 * sh + 16 * g) ^ x));
                oacc[s2] = __builtin_amdgcn_mfma_f32_16x16x32_bf16(pf, vf, oacc[s2], 0, 0, 0);
            }
        }

        if (st + 1 < NT) {
            char* Kn = cur ? Kb0 : Kb1;
            char* Vn = cur ? Vb0 : Vb1;
            #pragma unroll
            for (int c = 0; c < 2; ++c) {
                int row = c * 32 + srow;
                int sw  = scol ^ ((row & 7) << 4);
                *(uint4*)(Kn + row * 128 + sw) = kreg[c];
                *(uint4*)(Vn + row * 128 + sw) = vreg[c];
            }
            __syncthreads();
            cur ^= 1;
        }
    }

    // ---- epilogue: unnormalized O -> pctx; (m,l) -> pml ----
    float* pc = pctx + (size_t)sp * (L_ * NB * E_);
    #pragma unroll
    for (int r = 0; r < 4; ++r) {
        int q = qb0 + w * 16 + 4 * g + r;
        #pragma unroll
        for (int s2 = 0; s2 < 4; ++s2) {
            pc[((size_t)q * NB + n) * E_ + h * HD_ + s2 * 16 + c16] = oacc[s2][r];
        }
    }
    if (g == 0) {
        pml[(((size_t)sp * NB + n) * H_ + h) * L_ + qgl] = make_float2(mrun, lrun);
    }
}

// ---------------------------------------------------------------------------
// Combine the SPLIT partials -> ctx bf16 (L, NB, E)
// ---------------------------------------------------------------------------
__global__ __launch_bounds__(256)
void attn_combine_kernel(const float* __restrict__ pctx,
                         const float2* __restrict__ pml,
                         ushort_t* __restrict__ ctxb)
{
    int idx = blockIdx.x * 256 + threadIdx.x;     // over L*NB*E = 2M
    int h  = (idx >> 6) & 7;
    int tq = idx >> 9;
    int q = tq >> 2, n = tq & 3;
    float O0 = pctx[idx];
    float O1 = pctx[(size_t)(L_ * NB * E_) + idx];
    float2 ml0 = pml[(((size_t)0 * NB + n) * H_ + h) * L_ + q];
    float2 ml1 = pml[(((size_t)1 * NB + n) * H_ + h) * L_ + q];
    float ms = fmaxf(ml0.x, ml1.x);
    float a0 = __expf(ml0.x - ms), a1 = __expf(ml1.x - ms);
    float num = O0 * a0 + O1 * a1;
    float den = ml0.y * a0 + ml1.y * a1;
    ctxb[idx] = f2bf(num / den);
}

// ---------------------------------------------------------------------------
// LayerNorm (unchanged)
// ---------------------------------------------------------------------------
__global__ __launch_bounds__(256)
void ln_kernel(float* __restrict__ y, const float* __restrict__ gamma,
               const float* __restrict__ beta)
{
    __shared__ float red1[4], red2[4];
    const int row = blockIdx.x;
    const int t   = threadIdx.x;
    float* p = y + (size_t)row * E_;
    float x0 = p[t], x1 = p[t + 256];

    float s = x0 + x1;
    #pragma unroll
    for (int o = 32; o >= 1; o >>= 1) s += __shfl_down(s, o, 64);
    if ((t & 63) == 0) red1[t >> 6] = s;
    __syncthreads();
    const float mu = (red1[0] + red1[1] + red1[2] + red1[3]) * (1.0f / E_);

    const float d0 = x0 - mu, d1 = x1 - mu;
    float vs = d0 * d0 + d1 * d1;
    #pragma unroll
    for (int o = 32; o >= 1; o >>= 1) vs += __shfl_down(vs, o, 64);
    if ((t & 63) == 0) red2[t >> 6] = vs;
    __syncthreads();
    const float var  = (red2[0] + red2[1] + red2[2] + red2[3]) * (1.0f / E_);
    const float rstd = rsqrtf(var + LNEPS);

    p[t]       = d0 * rstd * gamma[t]       + beta[t];
    p[t + 256] = d1 * rstd * gamma[t + 256] + beta[t + 256];
}

extern "C" void kernel_launch(void* const* d_in, const int* in_sizes, int n_in,
                              void* d_out, int out_size, void* d_ws, size_t ws_size,
                              hipStream_t stream) {
    const float* query = (const float*)d_in[0];
    const float* value = (const float*)d_in[1];
    const float* qpos  = (const float*)d_in[2];
    const float* vpos  = (const float*)d_in[3];
    const float* ipw   = (const float*)d_in[4];
    const float* ipb   = (const float*)d_in[5];
    const float* opw   = (const float*)d_in[6];
    const float* opb   = (const float*)d_in[7];
    const float* gamma = (const float*)d_in[8];
    const float* beta  = (const float*)d_in[9];
    float* out = (float*)d_out;

    char* ws = (char*)d_ws;
    ushort_t* kvC   = (ushort_t*)(ws);                    // [0,16) MB (dead after epi_kv)
    ushort_t* vbf   = (ushort_t*)(ws + (16u << 20));      // [16,24) (dead after kv GEMM)
    ushort_t* qbf   = (ushort_t*)(ws + (24u << 20));      // [24,28) (dead after q GEMM)
    ushort_t* wbf   = (ushort_t*)(ws + (28u << 20));      // [28,29.5) (dead after GEMMs)
    ushort_t* obf   = (ushort_t*)(ws + (30u << 20));      // [30,30.5) (live to out GEMM)
    ushort_t* qC    = (ushort_t*)(ws + (31u << 20));      // [31,35)
    ushort_t* qrot  = (ushort_t*)(ws + (35u << 20));      // [35,39)
    ushort_t* krot  = (ushort_t*)(ws + (39u << 20));      // [39,47)
    ushort_t* vperm = (ushort_t*)(ws + (47u << 20));      // [47,55)
    ushort_t* vt    = (ushort_t*)(ws);                    // [0,8)  reuse kvC
    ushort_t* ctxb  = (ushort_t*)(ws + (8u << 20));       // [8,12) reuse kvC
    float2*   pml   = (float2*)  (ws + (12u << 20));      // [12,12.5) 512KB
    float*    pctx  = (float*)   (ws + (13u << 20));      // [13,29) 16MB (over dead vbf/qbf/wbf)

    const int c0 = 262144;
    const int c1 = c0 + 524288;
    const int c2 = c1 + 98304;
    const int c3 = c2 + 32768;
    cast4_kernel<<<3584, 256, 0, stream>>>(query, value, ipw, opw,
                                           qbf, vbf, wbf, obf, c0, c1, c2, c3);

    gemm_bf16_kernel<2, 0><<<dim3(512 / 128, 4096 / 64), 256, 0, stream>>>(
        qbf, wbf, qC, nullptr, nullptr, nullptr, 512);
    gemm_bf16_kernel<4, 0><<<dim3(1024 / 128, 8192 / 128), 256, 0, stream>>>(
        vbf, wbf + (size_t)E_ * E_, kvC, nullptr, nullptr, nullptr, 1024);

    epi_q_kernel<<<1024, 256, 0, stream>>>(qC, ipb, qpos, qrot);
    epi_kv_kernel<<<4096, 256, 0, stream>>>(kvC, ipb + E_, vpos, krot, vperm);

    vtrans_kernel<<<dim3(S_ / 64, H_, NB), 256, 0, stream>>>(vperm, vt);

    attn_mfma_kernel<<<dim3(L_ / 64, H_, NB * SPLIT), 256, 0, stream>>>(
        qrot, krot, vt, pctx, pml);
    attn_combine_kernel<<<(L_ * NB * E_) / 256, 256, 0, stream>>>(pctx, pml, ctxb);

    gemm_bf16_kernel<2, 1><<<dim3(512 / 128, 4096 / 64), 256, 0, stream>>>(
        ctxb, obf, nullptr, opb, query, out, 512);

    ln_kernel<<<L_ * NB, 256, 0, stream>>>(out, gamma, beta);
}